// Round 4
// baseline (268.257 us; speedup 1.0000x reference)
//
#include <hip/hip_runtime.h>
#include <hip/hip_bf16.h>

// WindowAttention — r8: single fused kernel, 2 independent blocks/CU.
//   All previous configs had ~1 block/CU (160KB LDS or VGPR cap) -> lockstep
//   phases, latency fully exposed (117us floor across 3 structures).
//   This version eliminates the shared Q/K/V/P LDS tensors (~100KB):
//     - wave = head (2 heads sequentially); Q/K re-layout via wave-private
//       8KB stripe (b64 packed writes, b128 frag reads, XOR swizzle);
//     - V re-layout fully in registers (cvt_pk + shfl lane exchange);
//     - softmax in swapped orientation (S^T): lane-local + shfl_xor(16/32);
//     - O parks in stripes; proj reads cross-wave after the ONLY mid barrier.
//   LDS = x 32KB (XOR) + 4 wave-stripes x 8KB + Qf 4KB = 68KB -> 2 blocks/CU.
//   Block 256 thr / 4 waves, grid 1024, 2 barriers, no global QKV/O scratch.

using short8  = __attribute__((ext_vector_type(8))) short;
using short4v = __attribute__((ext_vector_type(4))) short;
using floatx4 = __attribute__((ext_vector_type(4))) float;
using uint4v  = __attribute__((ext_vector_type(4))) unsigned int;

#define PI_F    3.14159265358979323846f
#define SCALE_F 0.17677669529663687f   // 32^-0.5

__device__ __forceinline__ short bfs(float x) {
  __hip_bfloat16 h = __float2bfloat16(x);
  return __builtin_bit_cast(short, h);
}

// pack two floats into one u32 of 2 bf16 (lo = a, hi = b)
__device__ __forceinline__ unsigned pk2(float a, float b) {
  unsigned lo = (unsigned short)bfs(a);
  unsigned hi = (unsigned short)bfs(b);
  return lo | (hi << 16);
}

// ---------------- kernel 1: weights fp32 -> bf16 into ws ----------------
__global__ void prep_kernel(const float* __restrict__ qw,
                            const float* __restrict__ pw,
                            __hip_bfloat16* __restrict__ dst) {
  int g = blockIdx.x * 256 + threadIdx.x;  // 65536 threads, one float4 each
  const float4* src;
  __hip_bfloat16* d;
  if (g < 49152) { src = (const float4*)qw + g; d = dst + g * 4; }
  else { int g2 = g - 49152; src = (const float4*)pw + g2; d = dst + 196608 + g2 * 4; }
  float4 v = *src;
  d[0] = __float2bfloat16(v.x);
  d[1] = __float2bfloat16(v.y);
  d[2] = __float2bfloat16(v.z);
  d[3] = __float2bfloat16(v.w);
}

__device__ __forceinline__ void fourier_feats(float dv, int col, float* f) {
  float s1, c1; __sincosf(PI_F * dv, &s1, &c1);
  float c2 = c1*c1 - s1*s1, s2 = 2.f*s1*c1;
  float c3 = c2*c1 - s2*s1, s3 = s2*c1 + c2*s1;
  float c4 = c2*c2 - s2*s2, s4 = 2.f*s2*c2;
  float sa1, ca1; __sincosf((2.f * PI_F / 64.f) * (float)col, &sa1, &ca1);
  float ca2 = ca1*ca1 - sa1*sa1, sa2 = 2.f*sa1*ca1;
  float ca3 = ca2*ca1 - sa2*sa1, sa3 = sa2*ca1 + ca2*sa1;
  float ca4 = ca2*ca2 - sa2*sa2, sa4 = 2.f*sa2*ca2;
  f[0]=c1;  f[1]=c2;  f[2]=c3;  f[3]=c4;
  f[4]=s1;  f[5]=s2;  f[6]=s3;  f[7]=s4;
  f[8]=ca1; f[9]=ca2; f[10]=ca3; f[11]=ca4;
  f[12]=sa1; f[13]=sa2; f[14]=sa3; f[15]=sa4;
}

// ---------------- fused per-window kernel ----------------
__global__ __launch_bounds__(256, 2) void win_kernel(
    const float* __restrict__ x, const float* __restrict__ D,
    const float* __restrict__ a_p, const float* __restrict__ b_p,
    const float* __restrict__ a_r, const float* __restrict__ b_r,
    const __hip_bfloat16* __restrict__ wq, const float* __restrict__ qkv_b,
    const __hip_bfloat16* __restrict__ pwb, const float* __restrict__ pb,
    float* __restrict__ out)
{
  // sX : x tile [64][256] bf16, XOR swizzle ((row&7)<<4) on 16B units
  // sStr: 4 wave-private 8KB stripes. Per head (bytes, within stripe):
  //   Q [64][32] @0..4095 -> frags ; K same @0..4095 ; Km [64][16] @0..2047 ;
  //   P half [32][64] @0..4095 (two passes) ; O_headA @4096..8191 ; O_headB @0..4095
  // sQf: raw Fourier feats [64][32] (16 feats + 16 zeros), XOR ((row&3)<<4)
  __shared__ __align__(16) __hip_bfloat16 sX  [64 * 256];   // 32768 B
  __shared__ __align__(16) __hip_bfloat16 sStr[4 * 4096];   // 32768 B
  __shared__ __align__(16) __hip_bfloat16 sQf [64 * 32];    //  4096 B
  // total 69632 B -> 2 blocks/CU

  const int tid = threadIdx.x;
  const int lane = tid & 63, w = tid >> 6;          // 4 waves
  const int laneN = lane & 15, laneQ = lane >> 4;
  const int b = blockIdx.x;
  const floatx4 fzero = {0.f, 0.f, 0.f, 0.f};
  const short8 zero8 = {0, 0, 0, 0, 0, 0, 0, 0};

  char* xb = (char*)sX;
  char* sb = (char*)sStr + w * 8192;   // this wave's stripe

  // ---- phase 0: raw feats (per-lane, kept in regs) + stage x + sQf ----
  float f[16];
  fourier_feats(D[b * 64 + lane], lane & 7, f);

  const float4* xg = (const float4*)(x + (size_t)b * 16384);
  #pragma unroll
  for (int it = 0; it < 16; ++it) {
    int g = tid + it * 256;
    float4 v = xg[g];
    int t = g >> 6;
    int off = (t * 512 + (g & 63) * 8) ^ ((t & 7) << 4);
    short4v pk = { bfs(v.x), bfs(v.y), bfs(v.z), bfs(v.w) };
    *(short4v*)(xb + off) = pk;
  }
  if (tid < 64) {   // wave 0 writes shared raw-feat tile (16 feats | 16 zeros)
    int t = tid;
    uint4v q0 = { pk2(f[0],f[1]),  pk2(f[2],f[3]),  pk2(f[4],f[5]),   pk2(f[6],f[7]) };
    uint4v q1 = { pk2(f[8],f[9]),  pk2(f[10],f[11]),pk2(f[12],f[13]), pk2(f[14],f[15]) };
    uint4v zz = { 0u, 0u, 0u, 0u };
    char* qb = (char*)sQf;
    *(uint4v*)(qb + ((t * 64 +  0) ^ ((t & 3) << 4))) = q0;
    *(uint4v*)(qb + ((t * 64 + 16) ^ ((t & 3) << 4))) = q1;
    *(uint4v*)(qb + ((t * 64 + 32) ^ ((t & 3) << 4))) = zz;
    *(uint4v*)(qb + ((t * 64 + 48) ^ ((t & 3) << 4))) = zz;
  }
  __syncthreads();   // barrier A

  // ---- per-head processing: wave w handles heads w and w+4 ----
  for (int hi = 0; hi < 2; ++hi) {
    const int hh = w + hi * 4;

    // ===== qkv GEMM for this head (Q,K swapped; V unswapped) =====
    floatx4 Qa[4][2], Ka[4][2], Va[4][2];
    #pragma unroll
    for (int mt = 0; mt < 4; ++mt)
      #pragma unroll
      for (int ont = 0; ont < 2; ++ont) { Qa[mt][ont]=fzero; Ka[mt][ont]=fzero; Va[mt][ont]=fzero; }

    const __hip_bfloat16* wqQ = wq + (size_t)(      hh*32 + laneN) * 256 + laneQ * 8;
    const __hip_bfloat16* wqK = wq + (size_t)(256 + hh*32 + laneN) * 256 + laneQ * 8;
    const __hip_bfloat16* wqV = wq + (size_t)(512 + hh*32 + laneN) * 256 + laneQ * 8;

    #pragma unroll
    for (int kk = 0; kk < 8; ++kk) {
      short8 a4[4];
      #pragma unroll
      for (int mt = 0; mt < 4; ++mt) {
        int off = ((mt*16 + laneN) * 512 + kk*64 + laneQ*16) ^ ((laneN & 7) << 4);
        a4[mt] = *(const short8*)(xb + off);
      }
      #pragma unroll
      for (int ont = 0; ont < 2; ++ont) {
        short8 fq = *(const short8*)(wqQ + (size_t)ont*16*256 + kk*32);
        short8 fk = *(const short8*)(wqK + (size_t)ont*16*256 + kk*32);
        short8 fv = *(const short8*)(wqV + (size_t)ont*16*256 + kk*32);
        #pragma unroll
        for (int mt = 0; mt < 4; ++mt) {
          Qa[mt][ont] = __builtin_amdgcn_mfma_f32_16x16x32_bf16(fq, a4[mt], Qa[mt][ont], 0, 0, 0);
          Ka[mt][ont] = __builtin_amdgcn_mfma_f32_16x16x32_bf16(fk, a4[mt], Ka[mt][ont], 0, 0, 0);
          Va[mt][ont] = __builtin_amdgcn_mfma_f32_16x16x32_bf16(a4[mt], fv, Va[mt][ont], 0, 0, 0);
        }
      }
    }

    // ===== Q -> stripe [64 tok][32 col] (XOR (row&3)<<4), read back as frags =====
    {
      float4 b0 = *(const float4*)&qkv_b[hh*32 +      laneQ*4];
      float4 b1 = *(const float4*)&qkv_b[hh*32 + 16 + laneQ*4];
      float qba[2][4] = {{b0.x,b0.y,b0.z,b0.w},{b1.x,b1.y,b1.z,b1.w}};
      #pragma unroll
      for (int mt = 0; mt < 4; ++mt)
        #pragma unroll
        for (int ont = 0; ont < 2; ++ont) {
          short4v pq;
          #pragma unroll
          for (int r = 0; r < 4; ++r)
            pq[r] = bfs((Qa[mt][ont][r] + qba[ont][r]) * SCALE_F);
          int off = ((mt*16 + laneN) * 64 + ont*32 + laneQ*8) ^ ((laneN & 3) << 4);
          *(short4v*)(sb + off) = pq;
        }
    }
    short8 qf[4];
    #pragma unroll
    for (int ct = 0; ct < 4; ++ct)
      qf[ct] = *(const short8*)(sb + (((ct*16 + laneN) * 64 + laneQ*16) ^ ((laneN & 3) << 4)));

    // ===== K -> same stripe region, frags =====
    {
      float4 b0 = *(const float4*)&qkv_b[256 + hh*32 +      laneQ*4];
      float4 b1 = *(const float4*)&qkv_b[256 + hh*32 + 16 + laneQ*4];
      float kba[2][4] = {{b0.x,b0.y,b0.z,b0.w},{b1.x,b1.y,b1.z,b1.w}};
      #pragma unroll
      for (int mt = 0; mt < 4; ++mt)
        #pragma unroll
        for (int ont = 0; ont < 2; ++ont) {
          short4v pk;
          #pragma unroll
          for (int r = 0; r < 4; ++r)
            pk[r] = bfs(Ka[mt][ont][r] + kba[ont][r]);
          int off = ((mt*16 + laneN) * 64 + ont*32 + laneQ*8) ^ ((laneN & 3) << 4);
          *(short4v*)(sb + off) = pk;
        }
    }
    short8 kf[4];
    #pragma unroll
    for (int rt = 0; rt < 4; ++rt)
      kf[rt] = *(const short8*)(sb + (((rt*16 + laneN) * 64 + laneQ*16) ^ ((laneN & 3) << 4)));

    // ===== Km (per-head mixed feats) [64 tok][16] -> stripe bytes 0..2047 =====
    {
      float m0[4], m1[4], m2[4], m3[4];
      #pragma unroll
      for (int p = 0; p < 4; ++p) {
        float ar = a_r[(p+1)*8 + hh], br = b_r[p*8 + hh];
        float ap = a_p[(p+1)*8 + hh], bp = b_p[p*8 + hh];
        m0[p] = (ar*f[p]     + br*f[4+p])  * 0.25f;
        m1[p] = (ar*f[4+p]   - br*f[p])    * 0.25f;
        m2[p] = (ap*f[8+p]   - bp*f[12+p]) * 0.25f;
        m3[p] = (ap*f[12+p]  + bp*f[8+p])  * 0.25f;
      }
      uint4v k0 = { pk2(m0[0],m0[1]), pk2(m0[2],m0[3]), pk2(m1[0],m1[1]), pk2(m1[2],m1[3]) };
      uint4v k1 = { pk2(m2[0],m2[1]), pk2(m2[2],m2[3]), pk2(m3[0],m3[1]), pk2(m3[2],m3[3]) };
      *(uint4v*)(sb + lane * 32)      = k0;
      *(uint4v*)(sb + lane * 32 + 16) = k1;
    }
    short8 kmf[4];
    #pragma unroll
    for (int rt = 0; rt < 4; ++rt) {
      short8 t8 = *(const short8*)(sb + (rt*16 + laneN) * 32 + (laneQ & 1) * 16);
      kmf[rt] = (laneQ < 2) ? t8 : zero8;
    }
    short8 qff[4];
    #pragma unroll
    for (int ct = 0; ct < 4; ++ct)
      qff[ct] = *(const short8*)((char*)sQf + (((ct*16 + laneN) * 64 + laneQ*16) ^ ((laneN & 3) << 4)));

    // ===== V^T frags fully in registers (pack + lane exchange) =====
    // vf[ont][kb] lane(laneN,laneQ) = V^T[dim ont*16+laneN][tok kb*32+laneQ*8+{0..7}]
    short8 vf[2][2];
    {
      float bv0 = qkv_b[512 + hh*32 +      laneN];
      float bv1 = qkv_b[512 + hh*32 + 16 + laneN];
      unsigned pkV[4][2][2];
      #pragma unroll
      for (int mt = 0; mt < 4; ++mt)
        #pragma unroll
        for (int ont = 0; ont < 2; ++ont) {
          float bv = ont ? bv1 : bv0;
          pkV[mt][ont][0] = pk2(Va[mt][ont][0] + bv, Va[mt][ont][1] + bv);
          pkV[mt][ont][1] = pk2(Va[mt][ont][2] + bv, Va[mt][ont][3] + bv);
        }
      int idxLo = laneN + 32 * (laneQ & 1);
      int idxHi = idxLo + 16;
      bool hiSel = (laneQ >= 2);
      #pragma unroll
      for (int ont = 0; ont < 2; ++ont)
        #pragma unroll
        for (int kb = 0; kb < 2; ++kb) {
          uint4v u;
          #pragma unroll
          for (int j = 0; j < 4; ++j) {
            int idx = (j < 2) ? idxLo : idxHi;
            unsigned lo = (unsigned)__shfl((int)pkV[2*kb    ][ont][j & 1], idx);
            unsigned hi = (unsigned)__shfl((int)pkV[2*kb + 1][ont][j & 1], idx);
            u[j] = hiSel ? hi : lo;
          }
          vf[ont][kb] = __builtin_bit_cast(short8, u);
        }
    }

    // ===== S^T = Kext * Qext^T  (32 MFMAs) =====
    floatx4 S[4][4];
    #pragma unroll
    for (int rt = 0; rt < 4; ++rt)
      #pragma unroll
      for (int ct = 0; ct < 4; ++ct) {
        S[rt][ct] = __builtin_amdgcn_mfma_f32_16x16x32_bf16(kf[rt], qf[ct], fzero, 0, 0, 0);
        S[rt][ct] = __builtin_amdgcn_mfma_f32_16x16x32_bf16(kmf[rt], qff[ct], S[rt][ct], 0, 0, 0);
      }

    // ===== softmax over k (rows of S^T): lane-local + shfl_xor(16/32) =====
    float inv4[4];
    #pragma unroll
    for (int ct = 0; ct < 4; ++ct) {
      float mx = S[0][ct][0];
      #pragma unroll
      for (int rt = 0; rt < 4; ++rt)
        #pragma unroll
        for (int r = 0; r < 4; ++r)
          mx = fmaxf(mx, S[rt][ct][r]);
      mx = fmaxf(mx, __shfl_xor(mx, 16));
      mx = fmaxf(mx, __shfl_xor(mx, 32));
      float sum = 0.f;
      #pragma unroll
      for (int rt = 0; rt < 4; ++rt)
        #pragma unroll
        for (int r = 0; r < 4; ++r) {
          S[rt][ct][r] = __expf(S[rt][ct][r] - mx);
          sum += S[rt][ct][r];
        }
      sum += __shfl_xor(sum, 16);
      sum += __shfl_xor(sum, 32);
      inv4[ct] = __builtin_amdgcn_rcpf(sum);
    }

    // ===== PV in two ct-halves via stripe P buffer [32][64] (XOR (row&7)<<4) =====
    floatx4 Oa[2][4];
    #pragma unroll
    for (int cp = 0; cp < 2; ++cp) {
      #pragma unroll
      for (int cc = 0; cc < 2; ++cc) {
        int ct = cp * 2 + cc;
        #pragma unroll
        for (int rt = 0; rt < 4; ++rt) {
          short4v pp;
          #pragma unroll
          for (int r = 0; r < 4; ++r)
            pp[r] = bfs(S[rt][ct][r] * inv4[ct]);
          int off = ((cc*16 + laneN) * 128 + rt*32 + laneQ*8) ^ ((laneN & 7) << 4);
          *(short4v*)(sb + off) = pp;
        }
      }
      #pragma unroll
      for (int cc = 0; cc < 2; ++cc) {
        int ct = cp * 2 + cc;
        short8 pf0 = *(const short8*)(sb + (((cc*16 + laneN) * 128 +  0 + laneQ*16) ^ ((laneN & 7) << 4)));
        short8 pf1 = *(const short8*)(sb + (((cc*16 + laneN) * 128 + 64 + laneQ*16) ^ ((laneN & 7) << 4)));
        #pragma unroll
        for (int ont = 0; ont < 2; ++ont) {
          Oa[ont][ct] = __builtin_amdgcn_mfma_f32_16x16x32_bf16(vf[ont][0], pf0, fzero, 0, 0, 0);
          Oa[ont][ct] = __builtin_amdgcn_mfma_f32_16x16x32_bf16(vf[ont][1], pf1, Oa[ont][ct], 0, 0, 0);
        }
      }
    }

    // ===== O -> stripe [64 tok][32 col] (headA @4096, headB @0) =====
    {
      int obase = hi ? 0 : 4096;
      #pragma unroll
      for (int ont = 0; ont < 2; ++ont)
        #pragma unroll
        for (int ct = 0; ct < 4; ++ct) {
          short4v po;
          #pragma unroll
          for (int r = 0; r < 4; ++r)
            po[r] = bfs(Oa[ont][ct][r]);
          int off = obase + (((ct*16 + laneN) * 64 + ont*32 + laneQ*8) ^ ((laneN & 3) << 4));
          *(short4v*)(sb + off) = po;
        }
    }
  }
  __syncthreads();   // barrier B — all O tiles parked in stripes

  // ---- proj GEMM: wave w owns out cols [64w, 64w+64) ----
  floatx4 pacc[4][4];
  #pragma unroll
  for (int mt = 0; mt < 4; ++mt)
    #pragma unroll
    for (int n = 0; n < 4; ++n) pacc[mt][n] = fzero;

  const __hip_bfloat16* pwr = pwb + (size_t)(w*64 + laneN) * 256 + laneQ * 8;
  #pragma unroll
  for (int kk = 0; kk < 8; ++kk) {        // kk == head index (32 dims each)
    char* ob = (char*)sStr + (kk & 3) * 8192 + ((kk < 4) ? 4096 : 0);
    short8 pa[4];
    #pragma unroll
    for (int mt = 0; mt < 4; ++mt)
      pa[mt] = *(const short8*)(ob + (((mt*16 + laneN) * 64 + laneQ*16) ^ ((laneN & 3) << 4)));
    short8 pw4[4];
    #pragma unroll
    for (int n = 0; n < 4; ++n)
      pw4[n] = *(const short8*)(pwr + (size_t)n*16*256 + kk*32);
    #pragma unroll
    for (int mt = 0; mt < 4; ++mt)
      #pragma unroll
      for (int n = 0; n < 4; ++n)
        pacc[mt][n] = __builtin_amdgcn_mfma_f32_16x16x32_bf16(pw4[n], pa[mt], pacc[mt][n], 0, 0, 0);
  }

  float* og = out + (size_t)b * 16384;
  #pragma unroll
  for (int n = 0; n < 4; ++n) {
    float4 b4 = *(const float4*)&pb[w*64 + n*16 + laneQ*4];
    #pragma unroll
    for (int mt = 0; mt < 4; ++mt) {
      float4 o4;
      o4.x = pacc[mt][n][0] + b4.x;
      o4.y = pacc[mt][n][1] + b4.y;
      o4.z = pacc[mt][n][2] + b4.z;
      o4.w = pacc[mt][n][3] + b4.w;
      *(float4*)&og[(mt*16 + laneN) * 256 + w*64 + n*16 + laneQ*4] = o4;
    }
  }
}

extern "C" void kernel_launch(void* const* d_in, const int* in_sizes, int n_in,
                              void* d_out, int out_size, void* d_ws, size_t ws_size,
                              hipStream_t stream) {
  const float* x      = (const float*)d_in[0];
  const float* D      = (const float*)d_in[1];
  const float* a_p    = (const float*)d_in[2];
  const float* b_p    = (const float*)d_in[3];
  const float* a_r    = (const float*)d_in[4];
  const float* b_r    = (const float*)d_in[5];
  const float* qkv_w  = (const float*)d_in[6];
  const float* qkv_b  = (const float*)d_in[7];
  const float* proj_w = (const float*)d_in[8];
  const float* proj_b = (const float*)d_in[9];

  __hip_bfloat16* wq  = (__hip_bfloat16*)d_ws;   // 196608 bf16 (qkv_w)
  __hip_bfloat16* pwb = wq + 196608;             // 65536 bf16 (proj_w)
  float* out = (float*)d_out;

  prep_kernel<<<256, 256, 0, stream>>>(qkv_w, proj_w, wq);
  win_kernel<<<1024, 256, 0, stream>>>(x, D, a_p, b_p, a_r, b_r, wq, qkv_b,
                                       pwb, proj_b, out);
}

// Round 5
// 233.655 us; speedup vs baseline: 1.1481x; 1.1481x over previous
//
#include <hip/hip_runtime.h>
#include <hip/hip_bf16.h>

// WindowAttention — r9: r8 structure (2 independent blocks/CU) made spill-free.
//   r8 failed on register pressure: fused Q/K/V GEMM kept 96 accs + frags live
//   -> ~200 arch regs vs ~128 budget -> ~250 MB scratch traffic (the 171 us).
//   Fixes, same skeleton (256 thr / 4 waves, wave = 2 heads, 8KB stripes,
//   2 barriers, 69.6 KB LDS -> 2 blocks/CU):
//     - Q+K GEMM pass (64 accs) then V GEMM pass (32 accs), never 96+.
//     - V^T re-layout via stripe (b64 writes / b128 frag reads, XOR swizzle)
//       instead of the register shuffle (kills pkV/shfl transients).
//     - strict stripe lifetime: Q->qf, K->kf, Km->kmf, V^T->vf, P, O-park.
//     - s_setprio around MFMA clusters (2 blocks at different phases).

using short8  = __attribute__((ext_vector_type(8))) short;
using short4v = __attribute__((ext_vector_type(4))) short;
using floatx4 = __attribute__((ext_vector_type(4))) float;
using uint4v  = __attribute__((ext_vector_type(4))) unsigned int;

#define PI_F    3.14159265358979323846f
#define SCALE_F 0.17677669529663687f   // 32^-0.5

__device__ __forceinline__ short bfs(float x) {
  __hip_bfloat16 h = __float2bfloat16(x);
  return __builtin_bit_cast(short, h);
}

__device__ __forceinline__ unsigned pk2(float a, float b) {
  unsigned lo = (unsigned short)bfs(a);
  unsigned hi = (unsigned short)bfs(b);
  return lo | (hi << 16);
}

// ---------------- kernel 1: weights fp32 -> bf16 into ws ----------------
__global__ void prep_kernel(const float* __restrict__ qw,
                            const float* __restrict__ pw,
                            __hip_bfloat16* __restrict__ dst) {
  int g = blockIdx.x * 256 + threadIdx.x;  // 65536 threads, one float4 each
  const float4* src;
  __hip_bfloat16* d;
  if (g < 49152) { src = (const float4*)qw + g; d = dst + g * 4; }
  else { int g2 = g - 49152; src = (const float4*)pw + g2; d = dst + 196608 + g2 * 4; }
  float4 v = *src;
  d[0] = __float2bfloat16(v.x);
  d[1] = __float2bfloat16(v.y);
  d[2] = __float2bfloat16(v.z);
  d[3] = __float2bfloat16(v.w);
}

__device__ __forceinline__ void fourier_feats(float dv, int col, float* f) {
  float s1, c1; __sincosf(PI_F * dv, &s1, &c1);
  float c2 = c1*c1 - s1*s1, s2 = 2.f*s1*c1;
  float c3 = c2*c1 - s2*s1, s3 = s2*c1 + c2*s1;
  float c4 = c2*c2 - s2*s2, s4 = 2.f*s2*c2;
  float sa1, ca1; __sincosf((2.f * PI_F / 64.f) * (float)col, &sa1, &ca1);
  float ca2 = ca1*ca1 - sa1*sa1, sa2 = 2.f*sa1*ca1;
  float ca3 = ca2*ca1 - sa2*sa1, sa3 = sa2*ca1 + ca2*sa1;
  float ca4 = ca2*ca2 - sa2*sa2, sa4 = 2.f*sa2*ca2;
  f[0]=c1;  f[1]=c2;  f[2]=c3;  f[3]=c4;
  f[4]=s1;  f[5]=s2;  f[6]=s3;  f[7]=s4;
  f[8]=ca1; f[9]=ca2; f[10]=ca3; f[11]=ca4;
  f[12]=sa1; f[13]=sa2; f[14]=sa3; f[15]=sa4;
}

// ---------------- fused per-window kernel ----------------
__global__ __launch_bounds__(256, 2) void win_kernel(
    const float* __restrict__ x, const float* __restrict__ D,
    const float* __restrict__ a_p, const float* __restrict__ b_p,
    const float* __restrict__ a_r, const float* __restrict__ b_r,
    const __hip_bfloat16* __restrict__ wq, const float* __restrict__ qkv_b,
    const __hip_bfloat16* __restrict__ pwb, const float* __restrict__ pb,
    float* __restrict__ out)
{
  // sX : x tile [64][256] bf16, XOR swizzle ((row&7)<<4) on 16B units
  // sStr: 4 wave-private 8KB stripes; per head, within-stripe lifetime:
  //   Q [64tok][32col]@0 -> qf ; K same@0 -> kf ; Km [64][16]@0 -> kmf ;
  //   V^T [32dim][64tok]@0 -> vf ; P [32][64]@0 (two ct-half passes) ;
  //   O_headA @4096..8191, O_headB @0..4095 (persist to proj)
  // sQf: raw Fourier feats [64][32] (16 feats + 16 zeros), XOR ((row&3)<<4)
  __shared__ __align__(16) __hip_bfloat16 sX  [64 * 256];   // 32768 B
  __shared__ __align__(16) __hip_bfloat16 sStr[4 * 4096];   // 32768 B
  __shared__ __align__(16) __hip_bfloat16 sQf [64 * 32];    //  4096 B
  // total 69632 B -> 2 blocks/CU

  const int tid = threadIdx.x;
  const int lane = tid & 63, w = tid >> 6;          // 4 waves
  const int laneN = lane & 15, laneQ = lane >> 4;
  const int b = blockIdx.x;
  const floatx4 fzero = {0.f, 0.f, 0.f, 0.f};
  const short8 zero8 = {0, 0, 0, 0, 0, 0, 0, 0};

  char* xb = (char*)sX;
  char* sb = (char*)sStr + w * 8192;   // this wave's stripe

  // ---- phase 0: raw feats (per-lane, kept in regs) + stage x + sQf ----
  float f[16];
  fourier_feats(D[b * 64 + lane], lane & 7, f);

  const float4* xg = (const float4*)(x + (size_t)b * 16384);
  #pragma unroll 4
  for (int it = 0; it < 16; ++it) {
    int g = tid + it * 256;
    float4 v = xg[g];
    int t = g >> 6;
    int off = (t * 512 + (g & 63) * 8) ^ ((t & 7) << 4);
    short4v pk = { bfs(v.x), bfs(v.y), bfs(v.z), bfs(v.w) };
    *(short4v*)(xb + off) = pk;
  }
  if (tid < 64) {   // wave 0 writes shared raw-feat tile (16 feats | 16 zeros)
    int t = tid;
    uint4v q0 = { pk2(f[0],f[1]),  pk2(f[2],f[3]),  pk2(f[4],f[5]),   pk2(f[6],f[7]) };
    uint4v q1 = { pk2(f[8],f[9]),  pk2(f[10],f[11]),pk2(f[12],f[13]), pk2(f[14],f[15]) };
    uint4v zz = { 0u, 0u, 0u, 0u };
    char* qb = (char*)sQf;
    *(uint4v*)(qb + ((t * 64 +  0) ^ ((t & 3) << 4))) = q0;
    *(uint4v*)(qb + ((t * 64 + 16) ^ ((t & 3) << 4))) = q1;
    *(uint4v*)(qb + ((t * 64 + 32) ^ ((t & 3) << 4))) = zz;
    *(uint4v*)(qb + ((t * 64 + 48) ^ ((t & 3) << 4))) = zz;
  }
  __syncthreads();   // barrier A

  // ---- per-head processing: wave w handles heads w and w+4 ----
  for (int hi = 0; hi < 2; ++hi) {
    const int hh = w + hi * 4;

    const __hip_bfloat16* wqQ = wq + (size_t)(      hh*32 + laneN) * 256 + laneQ * 8;
    const __hip_bfloat16* wqK = wq + (size_t)(256 + hh*32 + laneN) * 256 + laneQ * 8;
    const __hip_bfloat16* wqV = wq + (size_t)(512 + hh*32 + laneN) * 256 + laneQ * 8;

    // ===== pass 1: Q and K GEMM (swapped: D = [col][token]) =====
    floatx4 Qa[4][2], Ka[4][2];
    #pragma unroll
    for (int mt = 0; mt < 4; ++mt)
      #pragma unroll
      for (int ont = 0; ont < 2; ++ont) { Qa[mt][ont]=fzero; Ka[mt][ont]=fzero; }

    __builtin_amdgcn_s_setprio(1);
    #pragma unroll
    for (int kk = 0; kk < 8; ++kk) {
      short8 a4[4];
      #pragma unroll
      for (int mt = 0; mt < 4; ++mt) {
        int off = ((mt*16 + laneN) * 512 + kk*64 + laneQ*16) ^ ((laneN & 7) << 4);
        a4[mt] = *(const short8*)(xb + off);
      }
      #pragma unroll
      for (int ont = 0; ont < 2; ++ont) {
        short8 fq = *(const short8*)(wqQ + (size_t)ont*16*256 + kk*32);
        short8 fk = *(const short8*)(wqK + (size_t)ont*16*256 + kk*32);
        #pragma unroll
        for (int mt = 0; mt < 4; ++mt) {
          Qa[mt][ont] = __builtin_amdgcn_mfma_f32_16x16x32_bf16(fq, a4[mt], Qa[mt][ont], 0, 0, 0);
          Ka[mt][ont] = __builtin_amdgcn_mfma_f32_16x16x32_bf16(fk, a4[mt], Ka[mt][ont], 0, 0, 0);
        }
      }
    }
    __builtin_amdgcn_s_setprio(0);

    // ===== Q -> stripe [64 tok][32 col] (XOR (row&3)<<4), read back as frags =====
    {
      float4 b0 = *(const float4*)&qkv_b[hh*32 +      laneQ*4];
      float4 b1 = *(const float4*)&qkv_b[hh*32 + 16 + laneQ*4];
      float qba[2][4] = {{b0.x,b0.y,b0.z,b0.w},{b1.x,b1.y,b1.z,b1.w}};
      #pragma unroll
      for (int mt = 0; mt < 4; ++mt)
        #pragma unroll
        for (int ont = 0; ont < 2; ++ont) {
          short4v pq;
          #pragma unroll
          for (int r = 0; r < 4; ++r)
            pq[r] = bfs((Qa[mt][ont][r] + qba[ont][r]) * SCALE_F);
          int off = ((mt*16 + laneN) * 64 + ont*32 + laneQ*8) ^ ((laneN & 3) << 4);
          *(short4v*)(sb + off) = pq;
        }
    }
    short8 qf[4];
    #pragma unroll
    for (int ct = 0; ct < 4; ++ct)
      qf[ct] = *(const short8*)(sb + (((ct*16 + laneN) * 64 + laneQ*16) ^ ((laneN & 3) << 4)));

    // ===== K -> same stripe region (Q frags already in regs), read kf =====
    {
      float4 b0 = *(const float4*)&qkv_b[256 + hh*32 +      laneQ*4];
      float4 b1 = *(const float4*)&qkv_b[256 + hh*32 + 16 + laneQ*4];
      float kba[2][4] = {{b0.x,b0.y,b0.z,b0.w},{b1.x,b1.y,b1.z,b1.w}};
      #pragma unroll
      for (int mt = 0; mt < 4; ++mt)
        #pragma unroll
        for (int ont = 0; ont < 2; ++ont) {
          short4v pk;
          #pragma unroll
          for (int r = 0; r < 4; ++r)
            pk[r] = bfs(Ka[mt][ont][r] + kba[ont][r]);
          int off = ((mt*16 + laneN) * 64 + ont*32 + laneQ*8) ^ ((laneN & 3) << 4);
          *(short4v*)(sb + off) = pk;
        }
    }
    short8 kf[4];
    #pragma unroll
    for (int rt = 0; rt < 4; ++rt)
      kf[rt] = *(const short8*)(sb + (((rt*16 + laneN) * 64 + laneQ*16) ^ ((laneN & 3) << 4)));

    // ===== Km (per-head mixed feats) [64 tok][16] -> stripe 0..2047 =====
    {
      float m0[4], m1[4], m2[4], m3[4];
      #pragma unroll
      for (int p = 0; p < 4; ++p) {
        float ar = a_r[(p+1)*8 + hh], br = b_r[p*8 + hh];
        float ap = a_p[(p+1)*8 + hh], bp = b_p[p*8 + hh];
        m0[p] = (ar*f[p]     + br*f[4+p])  * 0.25f;
        m1[p] = (ar*f[4+p]   - br*f[p])    * 0.25f;
        m2[p] = (ap*f[8+p]   - bp*f[12+p]) * 0.25f;
        m3[p] = (ap*f[12+p]  + bp*f[8+p])  * 0.25f;
      }
      uint4v k0 = { pk2(m0[0],m0[1]), pk2(m0[2],m0[3]), pk2(m1[0],m1[1]), pk2(m1[2],m1[3]) };
      uint4v k1 = { pk2(m2[0],m2[1]), pk2(m2[2],m2[3]), pk2(m3[0],m3[1]), pk2(m3[2],m3[3]) };
      *(uint4v*)(sb + lane * 32)      = k0;
      *(uint4v*)(sb + lane * 32 + 16) = k1;
    }
    short8 kmf[4];
    #pragma unroll
    for (int rt = 0; rt < 4; ++rt) {
      short8 t8 = *(const short8*)(sb + (rt*16 + laneN) * 32 + (laneQ & 1) * 16);
      kmf[rt] = (laneQ < 2) ? t8 : zero8;
    }
    short8 qff[4];
    #pragma unroll
    for (int ct = 0; ct < 4; ++ct)
      qff[ct] = *(const short8*)((char*)sQf + (((ct*16 + laneN) * 64 + laneQ*16) ^ ((laneN & 3) << 4)));

    // ===== pass 2: V GEMM (unswapped: D = [token][vdim]) =====
    floatx4 Va[4][2];
    #pragma unroll
    for (int mt = 0; mt < 4; ++mt)
      #pragma unroll
      for (int ont = 0; ont < 2; ++ont) Va[mt][ont] = fzero;

    __builtin_amdgcn_s_setprio(1);
    #pragma unroll
    for (int kk = 0; kk < 8; ++kk) {
      short8 a4[4];
      #pragma unroll
      for (int mt = 0; mt < 4; ++mt) {
        int off = ((mt*16 + laneN) * 512 + kk*64 + laneQ*16) ^ ((laneN & 7) << 4);
        a4[mt] = *(const short8*)(xb + off);
      }
      #pragma unroll
      for (int ont = 0; ont < 2; ++ont) {
        short8 fv = *(const short8*)(wqV + (size_t)ont*16*256 + kk*32);
        #pragma unroll
        for (int mt = 0; mt < 4; ++mt)
          Va[mt][ont] = __builtin_amdgcn_mfma_f32_16x16x32_bf16(a4[mt], fv, Va[mt][ont], 0, 0, 0);
      }
    }
    __builtin_amdgcn_s_setprio(0);

    // ===== V^T -> stripe [32 dim][64 tok] (XOR (dim&7)<<4), read vf frags =====
    // lane holds D[tok mt*16+laneQ*4+r][vdim ont*16+laneN] -> 4 contiguous
    // tokens at fixed dim -> packed b64 along tok.
    {
      float bv0 = qkv_b[512 + hh*32 +      laneN];
      float bv1 = qkv_b[512 + hh*32 + 16 + laneN];
      #pragma unroll
      for (int mt = 0; mt < 4; ++mt)
        #pragma unroll
        for (int ont = 0; ont < 2; ++ont) {
          float bv = ont ? bv1 : bv0;
          short4v pv;
          #pragma unroll
          for (int r = 0; r < 4; ++r)
            pv[r] = bfs(Va[mt][ont][r] + bv);
          int off = ((ont*16 + laneN) * 128 + mt*32 + laneQ*8) ^ ((laneN & 7) << 4);
          *(short4v*)(sb + off) = pv;
        }
    }
    short8 vf[2][2];
    #pragma unroll
    for (int ont = 0; ont < 2; ++ont)
      #pragma unroll
      for (int kb = 0; kb < 2; ++kb)
        vf[ont][kb] = *(const short8*)(sb + (((ont*16 + laneN) * 128 + kb*64 + laneQ*16) ^ ((laneN & 7) << 4)));

    // ===== S^T = Kext * Qext^T (32 MFMAs) =====
    floatx4 S[4][4];
    __builtin_amdgcn_s_setprio(1);
    #pragma unroll
    for (int rt = 0; rt < 4; ++rt)
      #pragma unroll
      for (int ct = 0; ct < 4; ++ct) {
        S[rt][ct] = __builtin_amdgcn_mfma_f32_16x16x32_bf16(kf[rt], qf[ct], fzero, 0, 0, 0);
        S[rt][ct] = __builtin_amdgcn_mfma_f32_16x16x32_bf16(kmf[rt], qff[ct], S[rt][ct], 0, 0, 0);
      }
    __builtin_amdgcn_s_setprio(0);

    // ===== softmax over k (rows of S^T): lane-local + shfl_xor(16/32) =====
    float inv4[4];
    #pragma unroll
    for (int ct = 0; ct < 4; ++ct) {
      float mx = S[0][ct][0];
      #pragma unroll
      for (int rt = 0; rt < 4; ++rt)
        #pragma unroll
        for (int r = 0; r < 4; ++r)
          mx = fmaxf(mx, S[rt][ct][r]);
      mx = fmaxf(mx, __shfl_xor(mx, 16));
      mx = fmaxf(mx, __shfl_xor(mx, 32));
      float sum = 0.f;
      #pragma unroll
      for (int rt = 0; rt < 4; ++rt)
        #pragma unroll
        for (int r = 0; r < 4; ++r) {
          S[rt][ct][r] = __expf(S[rt][ct][r] - mx);
          sum += S[rt][ct][r];
        }
      sum += __shfl_xor(sum, 16);
      sum += __shfl_xor(sum, 32);
      inv4[ct] = __builtin_amdgcn_rcpf(sum);
    }

    // ===== PV in two ct-halves via stripe P buffer [32][64] (XOR (row&7)<<4) =====
    floatx4 Oa[2][4];
    #pragma unroll
    for (int cp = 0; cp < 2; ++cp) {
      #pragma unroll
      for (int cc = 0; cc < 2; ++cc) {
        int ct = cp * 2 + cc;
        #pragma unroll
        for (int rt = 0; rt < 4; ++rt) {
          short4v pp;
          #pragma unroll
          for (int r = 0; r < 4; ++r)
            pp[r] = bfs(S[rt][ct][r] * inv4[ct]);
          int off = ((cc*16 + laneN) * 128 + rt*32 + laneQ*8) ^ ((laneN & 7) << 4);
          *(short4v*)(sb + off) = pp;
        }
      }
      __builtin_amdgcn_s_setprio(1);
      #pragma unroll
      for (int cc = 0; cc < 2; ++cc) {
        int ct = cp * 2 + cc;
        short8 pf0 = *(const short8*)(sb + (((cc*16 + laneN) * 128 +  0 + laneQ*16) ^ ((laneN & 7) << 4)));
        short8 pf1 = *(const short8*)(sb + (((cc*16 + laneN) * 128 + 64 + laneQ*16) ^ ((laneN & 7) << 4)));
        #pragma unroll
        for (int ont = 0; ont < 2; ++ont) {
          Oa[ont][ct] = __builtin_amdgcn_mfma_f32_16x16x32_bf16(vf[ont][0], pf0, fzero, 0, 0, 0);
          Oa[ont][ct] = __builtin_amdgcn_mfma_f32_16x16x32_bf16(vf[ont][1], pf1, Oa[ont][ct], 0, 0, 0);
        }
      }
      __builtin_amdgcn_s_setprio(0);
    }

    // ===== O -> stripe [64 tok][32 col] (headA @4096, headB @0) =====
    {
      int obase = hi ? 0 : 4096;
      #pragma unroll
      for (int ont = 0; ont < 2; ++ont)
        #pragma unroll
        for (int ct = 0; ct < 4; ++ct) {
          short4v po;
          #pragma unroll
          for (int r = 0; r < 4; ++r)
            po[r] = bfs(Oa[ont][ct][r]);
          int off = obase + (((ct*16 + laneN) * 64 + ont*32 + laneQ*8) ^ ((laneN & 3) << 4));
          *(short4v*)(sb + off) = po;
        }
    }
  }
  __syncthreads();   // barrier B — all O tiles parked in stripes

  // ---- proj GEMM: wave w owns out cols [64w, 64w+64) ----
  floatx4 pacc[4][4];
  #pragma unroll
  for (int mt = 0; mt < 4; ++mt)
    #pragma unroll
    for (int n = 0; n < 4; ++n) pacc[mt][n] = fzero;

  const __hip_bfloat16* pwr = pwb + (size_t)(w*64 + laneN) * 256 + laneQ * 8;
  #pragma unroll
  for (int kk = 0; kk < 8; ++kk) {        // kk == head index (32 dims each)
    char* ob = (char*)sStr + (kk & 3) * 8192 + ((kk < 4) ? 4096 : 0);
    short8 pa[4];
    #pragma unroll
    for (int mt = 0; mt < 4; ++mt)
      pa[mt] = *(const short8*)(ob + (((mt*16 + laneN) * 64 + laneQ*16) ^ ((laneN & 3) << 4)));
    short8 pw4[4];
    #pragma unroll
    for (int n = 0; n < 4; ++n)
      pw4[n] = *(const short8*)(pwr + (size_t)n*16*256 + kk*32);
    __builtin_amdgcn_s_setprio(1);
    #pragma unroll
    for (int mt = 0; mt < 4; ++mt)
      #pragma unroll
      for (int n = 0; n < 4; ++n)
        pacc[mt][n] = __builtin_amdgcn_mfma_f32_16x16x32_bf16(pw4[n], pa[mt], pacc[mt][n], 0, 0, 0);
    __builtin_amdgcn_s_setprio(0);
  }

  float* og = out + (size_t)b * 16384;
  #pragma unroll
  for (int n = 0; n < 4; ++n) {
    float4 b4 = *(const float4*)&pb[w*64 + n*16 + laneQ*4];
    #pragma unroll
    for (int mt = 0; mt < 4; ++mt) {
      float4 o4;
      o4.x = pacc[mt][n][0] + b4.x;
      o4.y = pacc[mt][n][1] + b4.y;
      o4.z = pacc[mt][n][2] + b4.z;
      o4.w = pacc[mt][n][3] + b4.w;
      *(float4*)&og[(mt*16 + laneN) * 256 + w*64 + n*16 + laneQ*4] = o4;
    }
  }
}

extern "C" void kernel_launch(void* const* d_in, const int* in_sizes, int n_in,
                              void* d_out, int out_size, void* d_ws, size_t ws_size,
                              hipStream_t stream) {
  const float* x      = (const float*)d_in[0];
  const float* D      = (const float*)d_in[1];
  const float* a_p    = (const float*)d_in[2];
  const float* b_p    = (const float*)d_in[3];
  const float* a_r    = (const float*)d_in[4];
  const float* b_r    = (const float*)d_in[5];
  const float* qkv_w  = (const float*)d_in[6];
  const float* qkv_b  = (const float*)d_in[7];
  const float* proj_w = (const float*)d_in[8];
  const float* proj_b = (const float*)d_in[9];

  __hip_bfloat16* wq  = (__hip_bfloat16*)d_ws;   // 196608 bf16 (qkv_w)
  __hip_bfloat16* pwb = wq + 196608;             // 65536 bf16 (proj_w)
  float* out = (float*)d_out;

  prep_kernel<<<256, 256, 0, stream>>>(qkv_w, proj_w, wq);
  win_kernel<<<1024, 256, 0, stream>>>(x, D, a_p, b_p, a_r, b_r, wq, qkv_b,
                                       pwb, proj_b, out);
}